// Round 6
// baseline (768.704 us; speedup 1.0000x reference)
//
#include <hip/hip_runtime.h>
#include <hip/hip_fp16.h>

// Output layout (flat): forces[n_atoms*3] | virial[n_images*9] | stress[n_images*9]
//
// v6: k_scatter was store-TRANSACTION bound (12.8M random 8B stores ~= 40G/s,
// WRITE_SIZE ~ 12.8M x 32B sectors regardless of payload). Fix: per-chunk
// LDS counting sort so copy-out writes each bucket run contiguously
// (coalesced bursts instead of random 8B stores). k_gather: per-wave private
// LDS tiles to kill inter-wave same-address atomic serialization.

typedef unsigned int uint;
typedef unsigned short ushort;

#define SLICES  256         // count/scatter blocks (1024 threads each)
#define BASHIFT 8           // 256 atoms per bucket
#define NBCAP   1024        // max buckets (n_atoms <= 256k)
#define NVMAX   1152        // n_images*9 cap (128 images)
#define CHUNK_E 4096        // edges per sort-chunk (=> 8192 entries, 4/thread)
#define CHUNK_ENT (2*CHUNK_E)

__device__ __forceinline__ uint2 pack_entry(float dx, float dy, float dz, uint local) {
    const __half2 hxy = __floats2half2_rn(dx, dy);
    const ushort  hz  = __half_as_ushort(__float2half_rn(dz));
    uint2 r;
    r.x = *(const uint*)&hxy;
    r.y = (uint)hz | (local << 16);
    return r;
}

// ---------------- K1: per-(slice,bucket) histogram ----------------
__global__ __launch_bounds__(1024) void k_count(
    const int2* __restrict__ edge_idx, uint* __restrict__ counts,
    int n_edges, int es, int nb)
{
    __shared__ uint hist[NBCAP];
    for (int t = threadIdx.x; t < nb; t += blockDim.x) hist[t] = 0;
    __syncthreads();
    const int s  = blockIdx.x;
    const int e0 = s * es;
    const int e1 = min(n_edges, e0 + es);
    for (int e = e0 + threadIdx.x; e < e1; e += blockDim.x) {
        const int2 ij = edge_idx[e];
        atomicAdd(&hist[((uint)ij.x) >> BASHIFT], 1u);
        atomicAdd(&hist[((uint)ij.y) >> BASHIFT], 1u);
    }
    __syncthreads();
    for (int b = threadIdx.x; b < nb; b += blockDim.x)
        counts[(size_t)b * SLICES + s] = hist[b];   // bucket-major
}

// ---------------- K2a: row sums (one block per bucket) ----------------
__global__ __launch_bounds__(SLICES) void k_rowsum(
    const uint* __restrict__ counts, uint* __restrict__ rowsum)
{
    __shared__ uint red[SLICES];
    const int b = blockIdx.x;
    red[threadIdx.x] = counts[(size_t)b * SLICES + threadIdx.x];
    __syncthreads();
    for (int off = SLICES / 2; off > 0; off >>= 1) {
        if (threadIdx.x < off) red[threadIdx.x] += red[threadIdx.x + off];
        __syncthreads();
    }
    if (threadIdx.x == 0) rowsum[b] = red[0];
}

// ---------------- K2b: exclusive scan of row sums (single block) --------
__global__ __launch_bounds__(1024) void k_scan_rows(
    const uint* __restrict__ rowsum, uint* __restrict__ rowoff, int nb)
{
    __shared__ uint psum[1024];
    const int t = threadIdx.x;
    psum[t] = (t < nb) ? rowsum[t] : 0u;
    __syncthreads();
    for (int off = 1; off < 1024; off <<= 1) {
        uint v = (t >= off) ? psum[t - off] : 0u;
        __syncthreads();
        psum[t] += v;
        __syncthreads();
    }
    if (t < nb) rowoff[t] = (t == 0) ? 0u : psum[t - 1];
}

// ---------------- K2c: per-row exclusive scan + global offset ----------
__global__ __launch_bounds__(SLICES) void k_rowscan(
    uint* __restrict__ counts, const uint* __restrict__ rowoff)
{
    __shared__ uint psum[SLICES];
    const int b = blockIdx.x;
    const int t = threadIdx.x;
    const uint c = counts[(size_t)b * SLICES + t];
    psum[t] = c;
    __syncthreads();
    for (int off = 1; off < SLICES; off <<= 1) {
        uint v = (t >= off) ? psum[t - off] : 0u;
        __syncthreads();
        psum[t] += v;
        __syncthreads();
    }
    counts[(size_t)b * SLICES + t] = rowoff[b] + psum[t] - c;  // exclusive
}

// ---------------- K3: chunked LDS counting-sort scatter + virial --------
__global__ __launch_bounds__(1024) void k_scatter(
    const float* __restrict__ edge_diff, const float* __restrict__ dE_ddiff,
    const int2* __restrict__ edge_idx, const int* __restrict__ image_idx,
    const uint* __restrict__ offsets, uint2* __restrict__ entries,
    float* __restrict__ virial /* zeroed */, int n_edges, int es, int nb, int nv)
{
    __shared__ uint2 s_ent[CHUNK_ENT];   // 64 KB  staged payloads (bucket-sorted)
    __shared__ uint  s_dst[CHUNK_ENT];   // 32 KB  staged global destinations
    __shared__ uint  cnt[NBCAP];         // 4 KB   per-chunk bucket counts
    __shared__ uint  base[NBCAP];        // 4 KB   per-chunk exclusive scan
    __shared__ uint  tmp[1024];          // 4 KB   scan scratch
    __shared__ uint  gcur[NBCAP];        // 4 KB   per-slice global cursors
    __shared__ float lv[NVMAX];          // 4.5 KB virial accumulator

    const int s   = blockIdx.x;
    const int tid = threadIdx.x;

    for (int t = tid; t < nb; t += 1024) gcur[t] = offsets[(size_t)t * SLICES + s];
    for (int t = tid; t < nv; t += 1024) lv[t] = 0.f;
    __syncthreads();

    const int e0 = s * es;
    const int e1 = min(n_edges, e0 + es);

    for (int clo = e0; clo < e1; clo += CHUNK_E) {
        const int chi  = min(e1, clo + CHUNK_E);
        const int nent = 2 * (chi - clo);

        // phase 0: zero counts
        cnt[tid] = 0;
        __syncthreads();

        // phase 1: load edges, virial accumulate, rank within (chunk,bucket)
        uint2 ent_i[4], ent_j[4];
        uint  bi[4], bj[4], ri[4], rj[4];
        #pragma unroll
        for (int k = 0; k < 4; ++k) {
            const int e = clo + (k << 10) + tid;
            bi[k] = 0xffffffffu;
            if (e < chi) {
                const int2 ij = edge_idx[e];
                const float dx = dE_ddiff[3*e + 0];
                const float dy = dE_ddiff[3*e + 1];
                const float dz = dE_ddiff[3*e + 2];
                const uint ai = (uint)ij.x, aj = (uint)ij.y;
                bi[k] = ai >> BASHIFT;
                bj[k] = aj >> BASHIFT;
                ent_i[k] = pack_entry( dx,  dy,  dz, ai & ((1u << BASHIFT) - 1u));
                ent_j[k] = pack_entry(-dx, -dy, -dz, aj & ((1u << BASHIFT) - 1u));
                ri[k] = atomicAdd(&cnt[bi[k]], 1u);
                rj[k] = atomicAdd(&cnt[bj[k]], 1u);

                const float ex = edge_diff[3*e + 0];
                const float ey = edge_diff[3*e + 1];
                const float ez = edge_diff[3*e + 2];
                float* v = &lv[image_idx[ai] * 9];
                atomicAdd(&v[0], ex*dx); atomicAdd(&v[1], ex*dy); atomicAdd(&v[2], ex*dz);
                atomicAdd(&v[3], ey*dx); atomicAdd(&v[4], ey*dy); atomicAdd(&v[5], ey*dz);
                atomicAdd(&v[6], ez*dx); atomicAdd(&v[7], ez*dy); atomicAdd(&v[8], ez*dz);
            }
        }
        __syncthreads();

        // phase 2: exclusive scan cnt -> base (Hillis-Steele over 1024)
        const uint c0 = cnt[tid];
        tmp[tid] = c0;
        __syncthreads();
        for (int off = 1; off < 1024; off <<= 1) {
            const uint v = (tid >= off) ? tmp[tid - off] : 0u;
            __syncthreads();
            tmp[tid] += v;
            __syncthreads();
        }
        base[tid] = tmp[tid] - c0;
        __syncthreads();

        // phase 3: place into staging, bucket-sorted, with global dest
        #pragma unroll
        for (int k = 0; k < 4; ++k) {
            if (bi[k] != 0xffffffffu) {
                const uint pi = base[bi[k]] + ri[k];
                s_ent[pi] = ent_i[k];
                s_dst[pi] = gcur[bi[k]] + ri[k];
                const uint pj = base[bj[k]] + rj[k];
                s_ent[pj] = ent_j[k];
                s_dst[pj] = gcur[bj[k]] + rj[k];
            }
        }
        __syncthreads();

        // phase 4: coalesced copy-out (consecutive t -> consecutive dest per run)
        for (int t = tid; t < nent; t += 1024)
            entries[s_dst[t]] = s_ent[t];

        // phase 5: advance global cursors
        gcur[tid] += cnt[tid];
        __syncthreads();
    }

    // flush virial
    for (int t = tid; t < nv; t += 1024) {
        const float val = lv[t];
        if (val != 0.f) unsafeAtomicAdd(&virial[t], val);
    }
}

// ---------------- K4: gather per bucket -> forces (per-wave LDS tiles) ---
__global__ __launch_bounds__(256) void k_gather(
    const uint2* __restrict__ entries, const uint* __restrict__ offsets,
    float* __restrict__ forces, int n_atoms, int nb, uint total)
{
    __shared__ float tile[4][3 << BASHIFT];   // 4 waves x 3 KB
    const int q   = blockIdx.x;
    const int wid = threadIdx.x >> 6;
    for (int t = threadIdx.x; t < 4 * (3 << BASHIFT); t += blockDim.x)
        ((float*)tile)[t] = 0.f;
    __syncthreads();

    const uint beg = offsets[(size_t)q * SLICES];
    const uint end = (q + 1 < nb) ? offsets[(size_t)(q + 1) * SLICES] : total;
    float* wt = tile[wid];
    for (uint k = beg + threadIdx.x; k < end; k += blockDim.x) {
        const uint2 ent = entries[k];
        const float2 xy = __half22float2(*(const __half2*)&ent.x);
        const float  z  = __half2float(__ushort_as_half((ushort)(ent.y & 0xffffu)));
        const uint local = ent.y >> 16;
        atomicAdd(&wt[local*3 + 0], xy.x);
        atomicAdd(&wt[local*3 + 1], xy.y);
        atomicAdd(&wt[local*3 + 2], z);
    }
    __syncthreads();

    const int base = q << BASHIFT;
    const int lim3 = min(n_atoms - base, 1 << BASHIFT) * 3;
    for (int t = threadIdx.x; t < lim3; t += blockDim.x)
        forces[(size_t)base * 3 + t] = tile[0][t] + tile[1][t] + tile[2][t] + tile[3][t];
}

// ---------------- K5: stress ----------------
__global__ void k_stress(const float* __restrict__ cell,
                         const float* __restrict__ virial,
                         float* __restrict__ stress, int n_images)
{
    const int t = blockIdx.x * blockDim.x + threadIdx.x;
    if (t >= n_images * 9) return;
    const float* c = &cell[(t / 9) * 9];
    const float crx = c[4]*c[8] - c[5]*c[7];
    const float cry = c[5]*c[6] - c[3]*c[8];
    const float crz = c[3]*c[7] - c[4]*c[6];
    const float vol = c[0]*crx + c[1]*cry + c[2]*crz;
    stress[t] = virial[t] * (-1.0f / vol);
}

// ---------------- fallback (round-1) path ----------------
__global__ __launch_bounds__(256) void edge_kernel_fb(
    const float* __restrict__ edge_diff, const float* __restrict__ dE_ddiff,
    const int2* __restrict__ edge_idx, const int* __restrict__ image_idx,
    float* __restrict__ forces, float* __restrict__ virial,
    int n_edges, int n_images)
{
    extern __shared__ float lds_v[];
    const int nv = n_images * 9;
    for (int t = threadIdx.x; t < nv; t += blockDim.x) lds_v[t] = 0.f;
    __syncthreads();
    const int stride = gridDim.x * blockDim.x;
    for (int e = blockIdx.x * blockDim.x + threadIdx.x; e < n_edges; e += stride) {
        const int2 ij = edge_idx[e];
        const int i = ij.x, j = ij.y;
        const float dx = dE_ddiff[3*e+0], dy = dE_ddiff[3*e+1], dz = dE_ddiff[3*e+2];
        unsafeAtomicAdd(&forces[3*i+0],  dx);
        unsafeAtomicAdd(&forces[3*i+1],  dy);
        unsafeAtomicAdd(&forces[3*i+2],  dz);
        unsafeAtomicAdd(&forces[3*j+0], -dx);
        unsafeAtomicAdd(&forces[3*j+1], -dy);
        unsafeAtomicAdd(&forces[3*j+2], -dz);
        const float ex = edge_diff[3*e+0], ey = edge_diff[3*e+1], ez = edge_diff[3*e+2];
        float* v = &lds_v[image_idx[i] * 9];
        atomicAdd(&v[0], ex*dx); atomicAdd(&v[1], ex*dy); atomicAdd(&v[2], ex*dz);
        atomicAdd(&v[3], ey*dx); atomicAdd(&v[4], ey*dy); atomicAdd(&v[5], ey*dz);
        atomicAdd(&v[6], ez*dx); atomicAdd(&v[7], ez*dy); atomicAdd(&v[8], ez*dz);
    }
    __syncthreads();
    for (int t = threadIdx.x; t < nv; t += blockDim.x) {
        const float val = lds_v[t];
        if (val != 0.f) unsafeAtomicAdd(&virial[t], val);
    }
}

extern "C" void kernel_launch(void* const* d_in, const int* in_sizes, int n_in,
                              void* d_out, int out_size, void* d_ws, size_t ws_size,
                              hipStream_t stream)
{
    const float* edge_diff = (const float*)d_in[0];
    const float* dE_ddiff  = (const float*)d_in[1];
    const float* cell      = (const float*)d_in[2];
    const int2*  edge_idx  = (const int2*)d_in[3];
    const int*   image_idx = (const int*)d_in[4];

    const int n_edges  = in_sizes[0] / 3;
    const int n_images = in_sizes[2] / 9;
    const int n_atoms  = in_sizes[4];
    const int nv       = n_images * 9;

    float* out    = (float*)d_out;
    float* forces = out;
    float* virial = out + (size_t)n_atoms * 3;
    float* stress = virial + nv;

    const int nb = (n_atoms + (1 << BASHIFT) - 1) >> BASHIFT;
    const int es = (n_edges + SLICES - 1) / SLICES;
    const uint total = (uint)(2 * (size_t)n_edges);

    const size_t entries_bytes = (size_t)total * sizeof(uint2);
    const size_t counts_bytes  = (size_t)nb * SLICES * sizeof(uint);
    const size_t aux_bytes     = 2 * (size_t)NBCAP * sizeof(uint);
    const size_t need = entries_bytes + counts_bytes + aux_bytes;

    if (ws_size >= need && nb <= NBCAP && nv <= NVMAX) {
        uint2* entries = (uint2*)d_ws;
        uint*  offsets = (uint*)((char*)d_ws + entries_bytes);
        uint*  rowsum  = offsets + (size_t)nb * SLICES;
        uint*  rowoff  = rowsum + NBCAP;

        hipMemsetAsync(virial, 0, nv * sizeof(float), stream);

        k_count<<<SLICES, 1024, 0, stream>>>(edge_idx, offsets, n_edges, es, nb);
        k_rowsum<<<nb, SLICES, 0, stream>>>(offsets, rowsum);
        k_scan_rows<<<1, 1024, 0, stream>>>(rowsum, rowoff, nb);
        k_rowscan<<<nb, SLICES, 0, stream>>>(offsets, rowoff);
        k_scatter<<<SLICES, 1024, 0, stream>>>(edge_diff, dE_ddiff, edge_idx, image_idx,
                                               offsets, entries, virial, n_edges, es, nb, nv);
        k_gather<<<nb, 256, 0, stream>>>(entries, offsets, forces, n_atoms, nb, total);
        k_stress<<<(nv + 255) / 256, 256, 0, stream>>>(cell, virial, stress, n_images);
    } else {
        hipMemsetAsync(out, 0, ((size_t)n_atoms * 3 + nv) * sizeof(float), stream);
        edge_kernel_fb<<<2048, 256, nv * sizeof(float), stream>>>(
            edge_diff, dE_ddiff, edge_idx, image_idx, forces, virial, n_edges, n_images);
        k_stress<<<(nv + 255) / 256, 256, 0, stream>>>(cell, virial, stress, n_images);
    }
}

// Round 7
// 588.171 us; speedup vs baseline: 1.3069x; 1.3069x over previous
//
#include <hip/hip_runtime.h>
#include <hip/hip_fp16.h>

// Output layout (flat): forces[n_atoms*3] | virial[n_images*9] | stress[n_images*9]
//
// v7: (a) virial work moved out of k_scatter into k_gather, where each
// 256-atom bucket spans <=2 images -> register accumulation + wave reduce +
// ~18 global atomics per block. (b) uniform 16 B entries carrying both dE and
// edge_diff (fp16), coalesced copy-out kept from v6. (c) chunk scan is a
// two-level wave-shfl scan (2 barriers/chunk instead of 20).

typedef unsigned int uint;
typedef unsigned short ushort;

#define SLICES  256         // count/scatter blocks (1024 threads each)
#define BASHIFT 8           // 256 atoms per bucket
#define NBCAP   1024        // max buckets (n_atoms <= 256k)
#define NVMAX   1152        // n_images*9 cap
#define CHUNK_E 2048        // edges per sort-chunk => 4096 entries
#define CHUNK_ENT (2*CHUNK_E)

__device__ __forceinline__ uint pack_h2(float a, float b) {
    const __half2 h = __floats2half2_rn(a, b);
    return *(const uint*)&h;
}

// ---------------- K1: per-(slice,bucket) histogram ----------------
__global__ __launch_bounds__(1024) void k_count(
    const int2* __restrict__ edge_idx, uint* __restrict__ counts,
    int n_edges, int es, int nb)
{
    __shared__ uint hist[NBCAP];
    for (int t = threadIdx.x; t < nb; t += blockDim.x) hist[t] = 0;
    __syncthreads();
    const int s  = blockIdx.x;
    const int e0 = s * es;
    const int e1 = min(n_edges, e0 + es);
    for (int e = e0 + threadIdx.x; e < e1; e += blockDim.x) {
        const int2 ij = edge_idx[e];
        atomicAdd(&hist[((uint)ij.x) >> BASHIFT], 1u);
        atomicAdd(&hist[((uint)ij.y) >> BASHIFT], 1u);
    }
    __syncthreads();
    for (int b = threadIdx.x; b < nb; b += blockDim.x)
        counts[(size_t)b * SLICES + s] = hist[b];   // bucket-major
}

// ---------------- K2a: row sums ----------------
__global__ __launch_bounds__(SLICES) void k_rowsum(
    const uint* __restrict__ counts, uint* __restrict__ rowsum)
{
    __shared__ uint red[SLICES];
    const int b = blockIdx.x;
    red[threadIdx.x] = counts[(size_t)b * SLICES + threadIdx.x];
    __syncthreads();
    for (int off = SLICES / 2; off > 0; off >>= 1) {
        if (threadIdx.x < off) red[threadIdx.x] += red[threadIdx.x + off];
        __syncthreads();
    }
    if (threadIdx.x == 0) rowsum[b] = red[0];
}

// ---------------- K2b: exclusive scan of row sums ----------------
__global__ __launch_bounds__(1024) void k_scan_rows(
    const uint* __restrict__ rowsum, uint* __restrict__ rowoff, int nb)
{
    __shared__ uint psum[1024];
    const int t = threadIdx.x;
    psum[t] = (t < nb) ? rowsum[t] : 0u;
    __syncthreads();
    for (int off = 1; off < 1024; off <<= 1) {
        uint v = (t >= off) ? psum[t - off] : 0u;
        __syncthreads();
        psum[t] += v;
        __syncthreads();
    }
    if (t < nb) rowoff[t] = (t == 0) ? 0u : psum[t - 1];
}

// ---------------- K2c: per-row exclusive scan + global offset ----------
__global__ __launch_bounds__(SLICES) void k_rowscan(
    uint* __restrict__ counts, const uint* __restrict__ rowoff)
{
    __shared__ uint psum[SLICES];
    const int b = blockIdx.x;
    const int t = threadIdx.x;
    const uint c = counts[(size_t)b * SLICES + t];
    psum[t] = c;
    __syncthreads();
    for (int off = 1; off < SLICES; off <<= 1) {
        uint v = (t >= off) ? psum[t - off] : 0u;
        __syncthreads();
        psum[t] += v;
        __syncthreads();
    }
    counts[(size_t)b * SLICES + t] = rowoff[b] + psum[t] - c;  // exclusive
}

// ---------------- K3: chunked counting-sort scatter (no virial) ---------
// entry (uint4): x=h2(dEx,dEy)  y=h(dEz)|local<<16  z=h2(ex,ey)  w=h(ez)
// j-entries: negated dE, z=w=0 (contribute nothing to virial).
__global__ __launch_bounds__(1024) void k_scatter(
    const float* __restrict__ edge_diff, const float* __restrict__ dE_ddiff,
    const int2* __restrict__ edge_idx,
    const uint* __restrict__ offsets, uint4* __restrict__ entries,
    int n_edges, int es, int nb)
{
    __shared__ uint4 s_ent[CHUNK_ENT];   // 64 KB
    __shared__ uint  s_dst[CHUNK_ENT];   // 16 KB
    __shared__ uint  cnt[NBCAP];         // 4 KB
    __shared__ uint  base[NBCAP];        // 4 KB
    __shared__ uint  gcur[NBCAP];        // 4 KB
    __shared__ uint  wtot[16], wpre[16];

    const int s    = blockIdx.x;
    const int tid  = threadIdx.x;
    const int lane = tid & 63;
    const int wid  = tid >> 6;

    gcur[tid] = (tid < nb) ? offsets[(size_t)tid * SLICES + s] : 0u;
    __syncthreads();

    const int e0 = s * es;
    const int e1 = min(n_edges, e0 + es);

    for (int clo = e0; clo < e1; clo += CHUNK_E) {
        const int chi  = min(e1, clo + CHUNK_E);
        const int nent = 2 * (chi - clo);

        cnt[tid] = 0;
        __syncthreads();

        // phase 1: load, pack, rank
        uint4 ei[2], ej[2];
        uint  bi[2], bj[2], ri[2], rj[2];
        #pragma unroll
        for (int k = 0; k < 2; ++k) {
            const int e = clo + (k << 10) + tid;
            bi[k] = 0xffffffffu;
            if (e < chi) {
                const int2 ij = edge_idx[e];
                const float dx = dE_ddiff[3*e + 0];
                const float dy = dE_ddiff[3*e + 1];
                const float dz = dE_ddiff[3*e + 2];
                const float ex = edge_diff[3*e + 0];
                const float ey = edge_diff[3*e + 1];
                const float ez = edge_diff[3*e + 2];
                const uint ai = (uint)ij.x, aj = (uint)ij.y;
                bi[k] = ai >> BASHIFT;
                bj[k] = aj >> BASHIFT;
                const uint mask = (1u << BASHIFT) - 1u;
                ei[k].x = pack_h2(dx, dy);
                ei[k].y = (uint)__half_as_ushort(__float2half_rn(dz)) | ((ai & mask) << 16);
                ei[k].z = pack_h2(ex, ey);
                ei[k].w = (uint)__half_as_ushort(__float2half_rn(ez));
                ej[k].x = pack_h2(-dx, -dy);
                ej[k].y = (uint)__half_as_ushort(__float2half_rn(-dz)) | ((aj & mask) << 16);
                ej[k].z = 0u;
                ej[k].w = 0u;
                ri[k] = atomicAdd(&cnt[bi[k]], 1u);
                rj[k] = atomicAdd(&cnt[bj[k]], 1u);
            }
        }
        __syncthreads();

        // phase 2: two-level wave-shfl exclusive scan of cnt[1024]
        const uint c0 = cnt[tid];
        uint v = c0;
        #pragma unroll
        for (int off = 1; off < 64; off <<= 1) {
            const uint n = __shfl_up(v, off, 64);
            if (lane >= off) v += n;
        }
        if (lane == 63) wtot[wid] = v;
        __syncthreads();
        if (wid == 0) {
            uint t2 = (lane < 16) ? wtot[lane] : 0u;
            #pragma unroll
            for (int off = 1; off < 16; off <<= 1) {
                const uint n = __shfl_up(t2, off, 64);
                if (lane >= off) t2 += n;
            }
            if (lane < 16) wpre[lane] = t2 - wtot[lane];
        }
        __syncthreads();
        base[tid] = v - c0 + wpre[wid];
        __syncthreads();

        // phase 3: place into staging, bucket-sorted, with global dest
        #pragma unroll
        for (int k = 0; k < 2; ++k) {
            if (bi[k] != 0xffffffffu) {
                const uint pi = base[bi[k]] + ri[k];
                s_ent[pi] = ei[k];
                s_dst[pi] = gcur[bi[k]] + ri[k];
                const uint pj = base[bj[k]] + rj[k];
                s_ent[pj] = ej[k];
                s_dst[pj] = gcur[bj[k]] + rj[k];
            }
        }
        __syncthreads();

        // phase 4: coalesced copy-out
        for (int t = tid; t < nent; t += 1024)
            entries[s_dst[t]] = s_ent[t];

        // phase 5: advance cursors (cnt stable; gcur reads done pre-barrier)
        gcur[tid] += cnt[tid];
        __syncthreads();
    }
}

// ---------------- K4: gather -> forces + virial ----------------
__global__ __launch_bounds__(256) void k_gather(
    const uint4* __restrict__ entries, const uint* __restrict__ offsets,
    const int* __restrict__ image_idx,
    float* __restrict__ forces, float* __restrict__ virial /* zeroed */,
    int n_atoms, int nb, uint total)
{
    __shared__ float tile[4][3 << BASHIFT];   // 4 waves x 3 KB
    __shared__ int   s_img[1 << BASHIFT];     // 1 KB
    __shared__ float redA[4][9], redB[4][9];

    const int q    = blockIdx.x;
    const int tid  = threadIdx.x;
    const int wid  = tid >> 6;
    const int lane = tid & 63;
    const int batom = q << BASHIFT;

    {
        const int a = batom + tid;
        s_img[tid] = (a < n_atoms) ? image_idx[a] : -1;
    }
    for (int t = tid; t < 4 * (3 << BASHIFT); t += blockDim.x)
        ((float*)tile)[t] = 0.f;
    __syncthreads();

    const int nvalid = min(n_atoms - batom, 1 << BASHIFT);
    const int imgA = s_img[0];
    const int imgB = s_img[nvalid - 1];
    const bool hasB = (imgB != imgA);

    float accA[9] = {0,0,0,0,0,0,0,0,0};
    float accB[9] = {0,0,0,0,0,0,0,0,0};

    const uint beg = offsets[(size_t)q * SLICES];
    const uint end = (q + 1 < nb) ? offsets[(size_t)(q + 1) * SLICES] : total;
    float* wt = tile[wid];

    for (uint k = beg + tid; k < end; k += blockDim.x) {
        const uint4 ent = entries[k];
        const float2 dxy = __half22float2(*(const __half2*)&ent.x);
        const float  dz  = __half2float(__ushort_as_half((ushort)(ent.y & 0xffffu)));
        const uint local = (ent.y >> 16) & 0xffu;
        atomicAdd(&wt[local*3 + 0], dxy.x);
        atomicAdd(&wt[local*3 + 1], dxy.y);
        atomicAdd(&wt[local*3 + 2], dz);

        const float2 exy = __half22float2(*(const __half2*)&ent.z);
        const float  ez  = __half2float(__ushort_as_half((ushort)(ent.w & 0xffffu)));
        // j-entries have exy=ez=0 -> zero contribution.
        const int m = s_img[local];
        float p[9];
        p[0] = exy.x*dxy.x; p[1] = exy.x*dxy.y; p[2] = exy.x*dz;
        p[3] = exy.y*dxy.x; p[4] = exy.y*dxy.y; p[5] = exy.y*dz;
        p[6] = ez   *dxy.x; p[7] = ez   *dxy.y; p[8] = ez   *dz;
        const float wA = (m == imgA) ? 1.f : 0.f;
        const float wB = (hasB && m == imgB) ? 1.f : 0.f;
        #pragma unroll
        for (int c = 0; c < 9; ++c) { accA[c] += wA * p[c]; accB[c] += wB * p[c]; }
        if (m != imgA && m != imgB && m >= 0) {   // >2 images in bucket (rare)
            #pragma unroll
            for (int c = 0; c < 9; ++c) unsafeAtomicAdd(&virial[m*9 + c], p[c]);
        }
    }

    // wave-level reduce of accA/accB, then cross-wave via LDS
    #pragma unroll
    for (int c = 0; c < 9; ++c) {
        float a = accA[c], b = accB[c];
        #pragma unroll
        for (int off = 32; off > 0; off >>= 1) {
            a += __shfl_down(a, off, 64);
            b += __shfl_down(b, off, 64);
        }
        if (lane == 0) { redA[wid][c] = a; redB[wid][c] = b; }
    }
    __syncthreads();
    if (tid < 9) {
        const float sA = redA[0][tid] + redA[1][tid] + redA[2][tid] + redA[3][tid];
        unsafeAtomicAdd(&virial[imgA*9 + tid], sA);
        if (hasB) {
            const float sB = redB[0][tid] + redB[1][tid] + redB[2][tid] + redB[3][tid];
            unsafeAtomicAdd(&virial[imgB*9 + tid], sB);
        }
    }

    const int lim3 = nvalid * 3;
    for (int t = tid; t < lim3; t += blockDim.x)
        forces[(size_t)batom * 3 + t] = tile[0][t] + tile[1][t] + tile[2][t] + tile[3][t];
}

// ---------------- K5: stress ----------------
__global__ void k_stress(const float* __restrict__ cell,
                         const float* __restrict__ virial,
                         float* __restrict__ stress, int n_images)
{
    const int t = blockIdx.x * blockDim.x + threadIdx.x;
    if (t >= n_images * 9) return;
    const float* c = &cell[(t / 9) * 9];
    const float crx = c[4]*c[8] - c[5]*c[7];
    const float cry = c[5]*c[6] - c[3]*c[8];
    const float crz = c[3]*c[7] - c[4]*c[6];
    const float vol = c[0]*crx + c[1]*cry + c[2]*crz;
    stress[t] = virial[t] * (-1.0f / vol);
}

// ---------------- fallback (round-1) path ----------------
__global__ __launch_bounds__(256) void edge_kernel_fb(
    const float* __restrict__ edge_diff, const float* __restrict__ dE_ddiff,
    const int2* __restrict__ edge_idx, const int* __restrict__ image_idx,
    float* __restrict__ forces, float* __restrict__ virial,
    int n_edges, int n_images)
{
    extern __shared__ float lds_v[];
    const int nv = n_images * 9;
    for (int t = threadIdx.x; t < nv; t += blockDim.x) lds_v[t] = 0.f;
    __syncthreads();
    const int stride = gridDim.x * blockDim.x;
    for (int e = blockIdx.x * blockDim.x + threadIdx.x; e < n_edges; e += stride) {
        const int2 ij = edge_idx[e];
        const int i = ij.x, j = ij.y;
        const float dx = dE_ddiff[3*e+0], dy = dE_ddiff[3*e+1], dz = dE_ddiff[3*e+2];
        unsafeAtomicAdd(&forces[3*i+0],  dx);
        unsafeAtomicAdd(&forces[3*i+1],  dy);
        unsafeAtomicAdd(&forces[3*i+2],  dz);
        unsafeAtomicAdd(&forces[3*j+0], -dx);
        unsafeAtomicAdd(&forces[3*j+1], -dy);
        unsafeAtomicAdd(&forces[3*j+2], -dz);
        const float ex = edge_diff[3*e+0], ey = edge_diff[3*e+1], ez = edge_diff[3*e+2];
        float* v = &lds_v[image_idx[i] * 9];
        atomicAdd(&v[0], ex*dx); atomicAdd(&v[1], ex*dy); atomicAdd(&v[2], ex*dz);
        atomicAdd(&v[3], ey*dx); atomicAdd(&v[4], ey*dy); atomicAdd(&v[5], ey*dz);
        atomicAdd(&v[6], ez*dx); atomicAdd(&v[7], ez*dy); atomicAdd(&v[8], ez*dz);
    }
    __syncthreads();
    for (int t = threadIdx.x; t < nv; t += blockDim.x) {
        const float val = lds_v[t];
        if (val != 0.f) unsafeAtomicAdd(&virial[t], val);
    }
}

extern "C" void kernel_launch(void* const* d_in, const int* in_sizes, int n_in,
                              void* d_out, int out_size, void* d_ws, size_t ws_size,
                              hipStream_t stream)
{
    const float* edge_diff = (const float*)d_in[0];
    const float* dE_ddiff  = (const float*)d_in[1];
    const float* cell      = (const float*)d_in[2];
    const int2*  edge_idx  = (const int2*)d_in[3];
    const int*   image_idx = (const int*)d_in[4];

    const int n_edges  = in_sizes[0] / 3;
    const int n_images = in_sizes[2] / 9;
    const int n_atoms  = in_sizes[4];
    const int nv       = n_images * 9;

    float* out    = (float*)d_out;
    float* forces = out;
    float* virial = out + (size_t)n_atoms * 3;
    float* stress = virial + nv;

    const int nb = (n_atoms + (1 << BASHIFT) - 1) >> BASHIFT;
    const int es = (n_edges + SLICES - 1) / SLICES;
    const uint total = (uint)(2 * (size_t)n_edges);

    const size_t entries_bytes = (size_t)total * sizeof(uint4);
    const size_t counts_bytes  = (size_t)nb * SLICES * sizeof(uint);
    const size_t aux_bytes     = 2 * (size_t)NBCAP * sizeof(uint);
    const size_t need = entries_bytes + counts_bytes + aux_bytes;

    if (ws_size >= need && nb <= NBCAP && nv <= NVMAX) {
        uint4* entries = (uint4*)d_ws;
        uint*  offsets = (uint*)((char*)d_ws + entries_bytes);
        uint*  rowsum  = offsets + (size_t)nb * SLICES;
        uint*  rowoff  = rowsum + NBCAP;

        hipMemsetAsync(virial, 0, nv * sizeof(float), stream);

        k_count<<<SLICES, 1024, 0, stream>>>(edge_idx, offsets, n_edges, es, nb);
        k_rowsum<<<nb, SLICES, 0, stream>>>(offsets, rowsum);
        k_scan_rows<<<1, 1024, 0, stream>>>(rowsum, rowoff, nb);
        k_rowscan<<<nb, SLICES, 0, stream>>>(offsets, rowoff);
        k_scatter<<<SLICES, 1024, 0, stream>>>(edge_diff, dE_ddiff, edge_idx,
                                               offsets, entries, n_edges, es, nb);
        k_gather<<<nb, 256, 0, stream>>>(entries, offsets, image_idx,
                                         forces, virial, n_atoms, nb, total);
        k_stress<<<(nv + 255) / 256, 256, 0, stream>>>(cell, virial, stress, n_images);
    } else {
        hipMemsetAsync(out, 0, ((size_t)n_atoms * 3 + nv) * sizeof(float), stream);
        edge_kernel_fb<<<2048, 256, nv * sizeof(float), stream>>>(
            edge_diff, dE_ddiff, edge_idx, image_idx, forces, virial, n_edges, n_images);
        k_stress<<<(nv + 255) / 256, 256, 0, stream>>>(cell, virial, stress, n_images);
    }
}